// Round 1
// baseline (239.860 us; speedup 1.0000x reference)
//
#include <hip/hip_runtime.h>
#include <cstdint>

#define CC 256
#define TT 64
#define VV 7
#define KK 16384   // C*T
#define EE 256     // output features
#define LRELU_ALPHA 0.2f

typedef __bf16 bf16x8 __attribute__((ext_vector_type(8)));
typedef float f32x4 __attribute__((ext_vector_type(4)));

// ws layout (bytes):
//   [0, 16777216)            : partial f32 [8][256][2048]   (kchunk, o, m_global padded)
//   [16777216, 25165824)     : Wt bf16 [256][16384]
//   [25165824, +196)         : adj_norm f32 [49]
#define PARTIAL_OFF 0u
#define WT_OFF (8u*256u*2048u*4u)
#define ADJ_OFF (WT_OFF + 256u*16384u*2u)

__device__ __forceinline__ unsigned short f2bf(float f){
  union { float f; unsigned u; } x; x.f = f;
  unsigned r = x.u + 0x7fffu + ((x.u >> 16) & 1u);
  return (unsigned short)(r >> 16);
}

// ---------------- Kernel 1: W (16384x256 f32) -> Wt (256x16384 bf16) ----------------
__global__ __launch_bounds__(256) void k_transpose_w(const float* __restrict__ W,
                                                     unsigned short* __restrict__ Wt){
  __shared__ float tile[64][65];
  const int i0 = blockIdx.x * 64;
  const int o0 = blockIdx.y * 64;
  const int tid = threadIdx.x;
  #pragma unroll
  for (int r = 0; r < 16; ++r){
    int il = r*4 + (tid >> 6);
    int ol = tid & 63;
    tile[il][ol] = W[(size_t)(i0+il)*EE + o0 + ol];
  }
  __syncthreads();
  #pragma unroll
  for (int r = 0; r < 16; ++r){
    int ol = r*4 + (tid >> 6);
    int il = tid & 63;
    Wt[(size_t)(o0+ol)*KK + i0 + il] = f2bf(tile[il][ol]);
  }
}

// ---------------- Kernel 2: adj_norm (7x7) from Bp ----------------
__global__ void k_adj(const float* __restrict__ Bp, float* __restrict__ adjn){
  if (threadIdx.x == 0 && blockIdx.x == 0){
    float adj[49];
    float mn = 1e30f, mx = -1e30f;
    for (int i = 0; i < 7; ++i)
      for (int j = 0; j < 7; ++j){
        float x = Bp[i*7+j] + 1e-6f + (i == j ? 1.f : 0.f);
        adj[i*7+j] = x;
        mn = fminf(mn, x); mx = fmaxf(mx, x);
      }
    float inv = 1.f / (mx - mn);
    for (int i = 0; i < 49; ++i) adj[i] = (adj[i] - mn) * inv;
    float d12[7];
    for (int i = 0; i < 7; ++i){
      float s = 0.f;
      for (int j = 0; j < 7; ++j) s += adj[i*7+j];
      d12[i] = 1.f / sqrtf(s);
    }
    for (int i = 0; i < 7; ++i)
      for (int j = 0; j < 7; ++j)
        adjn[i*7+j] = d12[i] * adj[i*7+j] * d12[j];
  }
}

// ---------------- Kernel 3: main GEMM (split-K, fused h transpose+bf16) ----------------
// D[o][m] = sum_k Wt[o][k] * hf[m][k],  m = (n0+nn)*7+v rows (56 used, 64 padded)
// grid: (32 mtiles, 8 kchunks), 256 threads
__global__ __launch_bounds__(256) void k_gemm(const float* __restrict__ h,
                                              const unsigned short* __restrict__ Wt,
                                              float* __restrict__ part){
  __shared__ unsigned short As[256*72]; // Wt tile: o x k, stride 72
  __shared__ unsigned short Bs[64*72];  // h tile:  m x k, stride 72
  const int tid  = threadIdx.x;
  const int mt   = blockIdx.x;  // 0..31
  const int kc   = blockIdx.y;  // 0..7
  const int n0   = mt * 8;
  const int w    = tid >> 6;
  const int lane = tid & 63;
  const int col  = lane & 15;
  const int quad = lane >> 4;

  // zero pad rows (m = 56..63) once; staging never touches them
  for (int idx = tid; idx < 8*72; idx += 256) Bs[56*72 + idx] = 0;

  // hoisted h staging offsets (loop-invariant except + c*448)
  int hoff[14], hlds[14];
  #pragma unroll
  for (int it = 0; it < 14; ++it){
    int j  = tid + it*256;
    int nn = j / 448;
    int rr = j - nn*448;
    int t_ = rr / 7;
    int v_ = rr - t_*7;
    hoff[it] = (n0+nn)*114688 + rr;     // (n*C + c)*T*V base, c added later
    hlds[it] = (nn*7 + v_)*72 + t_;
  }
  const int wo = tid >> 3;        // 0..31
  const int wk = (tid & 7) * 8;   // 0..56

  f32x4 acc[4][4];
  #pragma unroll
  for (int a_ = 0; a_ < 4; ++a_)
    #pragma unroll
    for (int b_ = 0; b_ < 4; ++b_)
      acc[a_][b_] = (f32x4){0.f, 0.f, 0.f, 0.f};

  for (int s = 0; s < 32; ++s){
    const int c  = kc*32 + s;
    const int i0 = c*64;
    // stage Wt tile: 256 o x 64 k (bf16, already converted)
    {
      const unsigned short* src = Wt + (size_t)wo*KK + i0 + wk;
      #pragma unroll
      for (int r = 0; r < 8; ++r){
        float4 v = *reinterpret_cast<const float4*>(src + (size_t)r*32*KK);
        *reinterpret_cast<float4*>(&As[(wo + r*32)*72 + wk]) = v;
      }
    }
    // stage h tile: 8 n x 448 contiguous floats -> transposed bf16
    {
      const int cb = c*448;
      #pragma unroll
      for (int it = 0; it < 14; ++it){
        float val = h[(size_t)(hoff[it] + cb)];
        Bs[hlds[it]] = f2bf(val);
      }
    }
    __syncthreads();
    #pragma unroll
    for (int kh = 0; kh < 2; ++kh){
      bf16x8 af[4], bfr[4];
      #pragma unroll
      for (int oi = 0; oi < 4; ++oi)
        af[oi] = *reinterpret_cast<const bf16x8*>(&As[(w*64 + oi*16 + col)*72 + kh*32 + quad*8]);
      #pragma unroll
      for (int mi = 0; mi < 4; ++mi)
        bfr[mi] = *reinterpret_cast<const bf16x8*>(&Bs[(mi*16 + col)*72 + kh*32 + quad*8]);
      #pragma unroll
      for (int oi = 0; oi < 4; ++oi)
        #pragma unroll
        for (int mi = 0; mi < 4; ++mi)
          acc[oi][mi] = __builtin_amdgcn_mfma_f32_16x16x32_bf16(af[oi], bfr[mi], acc[oi][mi], 0, 0, 0);
    }
    __syncthreads();
  }

  // write partials: part[kc][o][mt*64 + m]
  #pragma unroll
  for (int oi = 0; oi < 4; ++oi){
    #pragma unroll
    for (int r = 0; r < 4; ++r){
      int o = w*64 + oi*16 + quad*4 + r;
      size_t rowbase = ((size_t)(kc*256 + o))*2048 + mt*64;
      #pragma unroll
      for (int mi = 0; mi < 4; ++mi)
        part[rowbase + mi*16 + col] = acc[oi][mi][r];
    }
  }
}

// ---------------- Kernel 4: reduce partials + attention + elu ----------------
// one block per n, thread = output feature o
__global__ __launch_bounds__(256) void k_attn(const float* __restrict__ part,
                                              const float* __restrict__ a,
                                              const float* __restrict__ adjn,
                                              float* __restrict__ out){
  const int n    = blockIdx.x;
  const int tid  = threadIdx.x;
  const int lane = tid & 63;
  const int wv   = tid >> 6;
  const int mt   = n >> 3;
  const int nn   = n & 7;
  const int bm   = mt*64 + nn*7;

  float wh[7];
  #pragma unroll
  for (int v = 0; v < 7; ++v){
    float s = 0.f;
    #pragma unroll
    for (int k = 0; k < 8; ++k)
      s += part[((size_t)(k*256 + tid))*2048 + bm + v];
    wh[v] = s;
  }

  const float a1 = a[tid];
  const float a2 = a[256 + tid];

  __shared__ float red1[4][7], red2[4][7];
  __shared__ float s1s[7], s2s[7];
  __shared__ float att0[49], att[49];

  #pragma unroll
  for (int v = 0; v < 7; ++v){
    float x1 = wh[v]*a1;
    float x2 = wh[v]*a2;
    #pragma unroll
    for (int off = 32; off > 0; off >>= 1){
      x1 += __shfl_down(x1, off);
      x2 += __shfl_down(x2, off);
    }
    if (lane == 0){ red1[wv][v] = x1; red2[wv][v] = x2; }
  }
  __syncthreads();
  if (tid < 7){
    s1s[tid] = red1[0][tid]+red1[1][tid]+red1[2][tid]+red1[3][tid];
    s2s[tid] = red2[0][tid]+red2[1][tid]+red2[2][tid]+red2[3][tid];
  }
  __syncthreads();
  if (tid < 7){
    const int v = tid;
    float e[7]; float mx = -1e30f;
    #pragma unroll
    for (int u = 0; u < 7; ++u){
      float t = s1s[v] + s2s[u];
      t = t > 0.f ? t : LRELU_ALPHA*t;
      e[u] = t; mx = fmaxf(mx, t);
    }
    float sum = 0.f;
    #pragma unroll
    for (int u = 0; u < 7; ++u){ e[u] = expf(e[u]-mx); sum += e[u]; }
    float inv = 1.f/sum;
    #pragma unroll
    for (int u = 0; u < 7; ++u) att0[v*7+u] = e[u]*inv;
  }
  __syncthreads();
  if (tid < 7){
    const int v = tid;
    #pragma unroll
    for (int u = 0; u < 7; ++u){
      float s = 0.f;
      #pragma unroll
      for (int w7 = 0; w7 < 7; ++w7) s += adjn[v*7+w7]*att0[w7*7+u];
      att[v*7+u] = s;
    }
  }
  __syncthreads();
  #pragma unroll
  for (int v = 0; v < 7; ++v){
    float hp = 0.f;
    #pragma unroll
    for (int u = 0; u < 7; ++u) hp += att[v*7+u]*wh[u];
    float o = hp > 0.f ? hp : expm1f(hp);
    out[(size_t)(n*7+v)*256 + tid] = o;
  }
}

extern "C" void kernel_launch(void* const* d_in, const int* in_sizes, int n_in,
                              void* d_out, int out_size, void* d_ws, size_t ws_size,
                              hipStream_t stream){
  const float* h  = (const float*)d_in[0];
  const float* W  = (const float*)d_in[1];
  const float* a  = (const float*)d_in[2];
  const float* Bp = (const float*)d_in[3];
  float* out = (float*)d_out;
  char* ws = (char*)d_ws;
  float*          part = (float*)(ws + PARTIAL_OFF);
  unsigned short* Wt   = (unsigned short*)(ws + WT_OFF);
  float*          adjn = (float*)(ws + ADJ_OFF);

  k_transpose_w<<<dim3(256, 4), 256, 0, stream>>>(W, Wt);
  k_adj<<<1, 64, 0, stream>>>(Bp, adjn);
  k_gemm<<<dim3(32, 8), 256, 0, stream>>>(h, Wt, part);
  k_attn<<<256, 256, 0, stream>>>(part, a, adjn, out);
}